// Round 2
// baseline (83.109 us; speedup 1.0000x reference)
//
#include <hip/hip_runtime.h>

// conv_capsules: extract overlapping 3x3 capsule patches.
// x: [B=8, H=64, W=64, C=16, D=16] f32 -> out: [B, OH=62, OW=62, KH=3, KW=3, C, D] f32
// out[b,oh,ow,kh,kw,c,d] = x[b,oh+kh,ow+kw,c,d]
// Block-per-tile: one block copies one (b,oh,ow) tile = 9 pixels x 1KB = 9KB.
// 192 threads x 3 float4 each, loads unrolled ahead of stores (3x MLP/wave).
// XCD swizzle: each XCD gets a contiguous tile range -> ~4.2MB input slab ~ L2.

constexpr int B  = 8;
constexpr int H  = 64;
constexpr int W  = 64;
constexpr int KH = 3;
constexpr int KW = 3;
constexpr int OH = H - KH + 1;   // 62
constexpr int OW = W - KW + 1;   // 62
constexpr int PIX4  = 64;        // float4 per (c,d) pixel block (256 floats)
constexpr int TILE4 = KH * KW * PIX4;  // 576 float4 per output tile
constexpr int NTILES = B * OH * OW;    // 30752
constexpr int NXCD = 8;

__global__ __launch_bounds__(192) void conv_capsules_patch_kernel(
    const float4* __restrict__ in, float4* __restrict__ out)
{
    // XCD-aware bijective swizzle (NTILES % 8 == 0): consecutive tiles on same XCD
    constexpr int CPX = NTILES / NXCD;  // 3844
    const int bid  = blockIdx.x;
    const int tile = (bid % NXCD) * CPX + (bid / NXCD);

    int t = tile;
    const int ow = t % OW; t /= OW;
    const int oh = t % OH;
    const int b  = t / OH;

    const int tid = threadIdx.x;  // 0..191

    float4 r0, r1, r2;
    // u = 0..2, j = tid + u*192, pixel p = j>>6 (0..8), lane = j&63
    {
        const int j = tid;
        const int p = j >> 6, lane = j & 63;
        const int kh = p / 3, kw = p - kh * 3;
        r0 = in[((b * H + oh + kh) * W + ow + kw) * PIX4 + lane];
    }
    {
        const int j = tid + 192;
        const int p = j >> 6, lane = j & 63;
        const int kh = p / 3, kw = p - kh * 3;
        r1 = in[((b * H + oh + kh) * W + ow + kw) * PIX4 + lane];
    }
    {
        const int j = tid + 384;
        const int p = j >> 6, lane = j & 63;
        const int kh = p / 3, kw = p - kh * 3;
        r2 = in[((b * H + oh + kh) * W + ow + kw) * PIX4 + lane];
    }

    float4* o = out + (long)tile * TILE4;
    o[tid]       = r0;
    o[tid + 192] = r1;
    o[tid + 384] = r2;
}

extern "C" void kernel_launch(void* const* d_in, const int* in_sizes, int n_in,
                              void* d_out, int out_size, void* d_ws, size_t ws_size,
                              hipStream_t stream)
{
    const float4* in  = (const float4*)d_in[0];
    float4*       out = (float4*)d_out;
    conv_capsules_patch_kernel<<<NTILES, 192, 0, stream>>>(in, out);
}

// Round 3
// 63.158 us; speedup vs baseline: 1.3159x; 1.3159x over previous
//
#include <hip/hip_runtime.h>

// conv_capsules patch extraction, SCATTER formulation.
// x: [B=8, H=64, W=64, C=16, D=16] f32 -> out: [B, OH=62, OW=62, KH=3, KW=3, C, D]
// out[b,oh,ow,kh,kw] = x[b,oh+kh,ow+kw]  (each "pixel" = C*D = 256 floats = 1KB)
//
// Gather version hit the HBM ceiling at 566 MB (9x read amplification: the
// 283 MB write stream evicts the 33.5 MB input from L2/L3). Scatter reads each
// input pixel ONCE (registers), then stores it to its <=9 output slots:
// 1 wave per pixel, 64 lanes x float4 = 1KB in-reg, 9 coalesced 1KB stores.
// Bounds checks are wave-uniform (h,w uniform per wave) -> no divergence.

constexpr int B  = 8;
constexpr int H  = 64;
constexpr int W  = 64;
constexpr int KH = 3;
constexpr int KW = 3;
constexpr int OH = H - KH + 1;   // 62
constexpr int OW = W - KW + 1;   // 62
constexpr int PIX4  = 64;        // float4 per pixel (256 floats)
constexpr int TILE4 = KH * KW * PIX4;  // 576 float4 per output tile
constexpr int NPIX  = B * H * W;       // 32768 pixels

__global__ __launch_bounds__(256) void conv_capsules_scatter_kernel(
    const float4* __restrict__ in, float4* __restrict__ out)
{
    const int gtid = blockIdx.x * 256 + threadIdx.x;
    const int pix  = gtid >> 6;          // global wave id = input pixel
    const int lane = gtid & 63;

    const int b = pix >> 12;             // pix / (64*64)
    const int h = (pix >> 6) & 63;
    const int w = pix & 63;

    const float4 v = in[pix * PIX4 + lane];

    #pragma unroll
    for (int kh = 0; kh < KH; ++kh) {
        const int oh = h - kh;
        if ((unsigned)oh >= (unsigned)OH) continue;   // wave-uniform
        #pragma unroll
        for (int kw = 0; kw < KW; ++kw) {
            const int ow = w - kw;
            if ((unsigned)ow >= (unsigned)OW) continue;
            const int tile = (b * OH + oh) * OW + ow;
            out[tile * TILE4 + (kh * KW + kw) * PIX4 + lane] = v;
        }
    }
}

extern "C" void kernel_launch(void* const* d_in, const int* in_sizes, int n_in,
                              void* d_out, int out_size, void* d_ws, size_t ws_size,
                              hipStream_t stream)
{
    const float4* in  = (const float4*)d_in[0];
    float4*       out = (float4*)d_out;
    // 32768 pixels, 1 wave each, 4 waves per 256-thread block -> 8192 blocks
    conv_capsules_scatter_kernel<<<NPIX / 4, 256, 0, stream>>>(in, out);
}

// Round 4
// 60.034 us; speedup vs baseline: 1.3844x; 1.0520x over previous
//
#include <hip/hip_runtime.h>

// conv_capsules patch extraction, SCATTER formulation, 4 pixels/wave.
// x: [B=8, H=64, W=64, C=16, D=16] f32 -> out: [B, OH=62, OW=62, KH=3, KW=3, C, D]
// out[b,oh,ow,kh,kw] = x[b,oh+kh,ow+kw]   (pixel = C*D = 256 floats = 1KB)
//
// R3 scatter (1 px/wave) = 63 us = 5.0 TB/s on 317 MB. Gap vs 6.3 TB/s copy
// ceiling attributed to tiny waves: 1 load -> vmcnt(0) -> 9 stores, no MLP.
// Here: each wave owns 4 consecutive-w pixels (4 independent 1KB loads in
// flight), interior waves take a branch-free 36-store path.

constexpr int OH = 62;
constexpr int OW = 62;
constexpr int PIX4  = 64;               // float4 per pixel
constexpr int TILE4 = 9 * PIX4;         // 576 float4 per output tile

__global__ __launch_bounds__(256) void conv_capsules_scatter4_kernel(
    const float4* __restrict__ in, float4* __restrict__ out)
{
    const int gtid = blockIdx.x * 256 + threadIdx.x;
    const int wave = gtid >> 6;          // 8192 waves
    const int lane = gtid & 63;

    const int w0 = (wave & 15) * 4;      // 0,4,...,60
    const int h  = (wave >> 4) & 63;
    const int b  = wave >> 10;

    // 4 contiguous pixel loads (4 KB), all issued before first use
    const float4* ip = in + ((((b << 6) | h) << 6 | w0) << 6) + lane;
    const float4 v0 = ip[0];
    const float4 v1 = ip[64];
    const float4 v2 = ip[128];
    const float4 v3 = ip[192];

    const bool interior = (h >= 2) & (h <= 61) & (w0 >= 4) & (w0 <= 56);

    if (interior) {
        // all 4 pixels have all 9 slots valid
        #pragma unroll
        for (int kh = 0; kh < 3; ++kh) {
            const int rb = ((b * OH + (h - kh)) * OW + w0) * TILE4
                         + kh * 3 * PIX4 + lane;
            #pragma unroll
            for (int kw = 0; kw < 3; ++kw) {
                const int base = rb - kw * TILE4 + kw * PIX4;
                out[base]             = v0;
                out[base + TILE4]     = v1;
                out[base + 2 * TILE4] = v2;
                out[base + 3 * TILE4] = v3;
            }
        }
    } else {
        #pragma unroll
        for (int p = 0; p < 4; ++p) {
            const float4 v = (p == 0) ? v0 : (p == 1) ? v1 : (p == 2) ? v2 : v3;
            const int w = w0 + p;
            #pragma unroll
            for (int kh = 0; kh < 3; ++kh) {
                const int oh = h - kh;
                if ((unsigned)oh >= (unsigned)OH) continue;
                #pragma unroll
                for (int kw = 0; kw < 3; ++kw) {
                    const int ow = w - kw;
                    if ((unsigned)ow >= (unsigned)OW) continue;
                    out[((b * OH + oh) * OW + ow) * TILE4
                        + (kh * 3 + kw) * PIX4 + lane] = v;
                }
            }
        }
    }
}

extern "C" void kernel_launch(void* const* d_in, const int* in_sizes, int n_in,
                              void* d_out, int out_size, void* d_ws, size_t ws_size,
                              hipStream_t stream)
{
    const float4* in  = (const float4*)d_in[0];
    float4*       out = (float4*)d_out;
    // 32768 pixels / 4 per wave = 8192 waves; 4 waves/block -> 2048 blocks
    conv_capsules_scatter4_kernel<<<2048, 256, 0, stream>>>(in, out);
}